// Round 6
// baseline (198.551 us; speedup 1.0000x reference)
//
#include <hip/hip_runtime.h>
#include <math.h>

#define NS     512
#define NOBJ   16
#define MPTS   8192
#define HH     128
#define WW     128
#define HW     (HH * WW)
#define BLOCK  256
#define PSPLIT 8                              // pixel chunks per sample
#define MSPLIT 4                              // mesh chunks per sample
#define P_IT   (HW / 4 / PSPLIT / BLOCK)      // 2 float4-groups per thread
#define M_IT   (MPTS / MSPLIT / (BLOCK * 4))  // 2 x 4-point groups per thread
#define NWAVE  (BLOCK / 64)

__device__ __forceinline__ float frcp(float x)  { return __builtin_amdgcn_rcpf(x); }
__device__ __forceinline__ float fsqrt(float x) { return __builtin_amdgcn_sqrtf(x); }
__device__ __forceinline__ float rfl(float x) {
    return __int_as_float(__builtin_amdgcn_readfirstlane(__float_as_int(x)));
}

// Build the fused projection matrix rows (K*R, K*t) as SGPR-resident floats.
__device__ __forceinline__ void fuse_proj(const float* __restrict__ cam_K,
                                          const float* __restrict__ R,
                                          const float* __restrict__ t, int n,
                                          float A[9], float b[3]) {
    float K[9], Rr[9], tt[3];
#pragma unroll
    for (int i = 0; i < 9; ++i) { K[i] = cam_K[n * 9 + i]; Rr[i] = R[n * 9 + i]; }
#pragma unroll
    for (int i = 0; i < 3; ++i) tt[i] = t[n * 3 + i];
#pragma unroll
    for (int r = 0; r < 3; ++r) {
#pragma unroll
        for (int c = 0; c < 3; ++c)
            A[r * 3 + c] = rfl(K[r * 3 + 0] * Rr[0 * 3 + c]
                             + K[r * 3 + 1] * Rr[1 * 3 + c]
                             + K[r * 3 + 2] * Rr[2 * 3 + c]);
        b[r] = rfl(K[r * 3 + 0] * tt[0] + K[r * 3 + 1] * tt[1] + K[r * 3 + 2] * tt[2]);
    }
}

// ---------------- kernel 1: pixel stream (pv partials) ----------------
// Pure streamer: 8 batched dwordx4 loads per thread, then compute. Nothing else.
__global__ __launch_bounds__(BLOCK) void score_pixels(
    const float* __restrict__ cam_K,
    const float* __restrict__ gt_R,
    const float* __restrict__ gt_t,
    const float* __restrict__ pr_R,
    const float* __restrict__ pr_t,
    const float* __restrict__ coord,      // [N,3,H,W]
    const int*   __restrict__ mask,       // [N,1,H,W]
    float*       __restrict__ wsB)        // [N,PSPLIT,2] : pv, m
{
    const int b   = blockIdx.x;
    const int n   = b >> 3;
    const int c   = b & (PSPLIT - 1);
    const int tid = threadIdx.x;

    // issue all loads first
    const float* cx = coord + (size_t)n * 3 * HW;
    const float4* cx4 = (const float4*)cx;
    const float4* cy4 = (const float4*)(cx + HW);
    const float4* cz4 = (const float4*)(cx + 2 * HW);
    const int4*   mk4 = (const int4*)(mask + (size_t)n * HW);

    float4 AX[P_IT], AY[P_IT], AZ[P_IT];
    int4   AM[P_IT];
#pragma unroll
    for (int it = 0; it < P_IT; ++it) {
        const int p = c * (HW / 4 / PSPLIT) + it * BLOCK + tid;
        AX[it] = cx4[p];
        AY[it] = cy4[p];
        AZ[it] = cz4[p];
        AM[it] = mk4[p];
    }

    // constants (scalar work, overlaps load latency)
    float Ap[9], Ag[9], bp[3], bg[3];
    fuse_proj(cam_K, pr_R, pr_t, n, Ap, bp);
    fuse_proj(cam_K, gt_R, gt_t, n, Ag, bg);

    float s_pv = 0.0f, s_m = 0.0f;
#pragma unroll
    for (int it = 0; it < P_IT; ++it) {
        const float xs[4] = {AX[it].x, AX[it].y, AX[it].z, AX[it].w};
        const float ys[4] = {AY[it].x, AY[it].y, AY[it].z, AY[it].w};
        const float zs[4] = {AZ[it].x, AZ[it].y, AZ[it].z, AZ[it].w};
        const int   ms[4] = {AM[it].x, AM[it].y, AM[it].z, AM[it].w};
#pragma unroll
        for (int j = 0; j < 4; ++j) {
            const float x = xs[j], y = ys[j], z = zs[j];
            const float hpx = fmaf(Ap[0], x, fmaf(Ap[1], y, fmaf(Ap[2], z, bp[0])));
            const float hpy = fmaf(Ap[3], x, fmaf(Ap[4], y, fmaf(Ap[5], z, bp[1])));
            const float hpz = fmaf(Ap[6], x, fmaf(Ap[7], y, fmaf(Ap[8], z, bp[2])));
            const float hgx = fmaf(Ag[0], x, fmaf(Ag[1], y, fmaf(Ag[2], z, bg[0])));
            const float hgy = fmaf(Ag[3], x, fmaf(Ag[4], y, fmaf(Ag[5], z, bg[1])));
            const float hgz = fmaf(Ag[6], x, fmaf(Ag[7], y, fmaf(Ag[8], z, bg[2])));
            const float iwp = frcp(hpz), iwg = frcp(hgz);
            const float du = fmaf(hpx, iwp, -hgx * iwg);
            const float dv = fmaf(hpy, iwp, -hgy * iwg);
            const float d  = fsqrt(fmaf(du, du, dv * dv));
            const float fm = (ms[j] != 0) ? 1.0f : 0.0f;
            s_pv += d * fm;
            s_m  += fm;
        }
    }

    // block reduce (2 values)
    float vals[2] = {s_pv, s_m};
#pragma unroll
    for (int k = 0; k < 2; ++k)
#pragma unroll
        for (int off = 32; off > 0; off >>= 1)
            vals[k] += __shfl_down(vals[k], off, 64);

    __shared__ float red[2][NWAVE];
    const int wave = tid >> 6, lane = tid & 63;
    if (lane == 0) { red[0][wave] = vals[0]; red[1][wave] = vals[1]; }
    __syncthreads();
    if (tid == 0) {
        float pv = 0.0f, m = 0.0f;
#pragma unroll
        for (int w = 0; w < NWAVE; ++w) { pv += red[0][w]; m += red[1][w]; }
        wsB[(size_t)(n * PSPLIT + c) * 2 + 0] = pv;
        wsB[(size_t)(n * PSPLIT + c) * 2 + 1] = m;
    }
}

// ---------------- kernel 2: mesh phase (ad + pj partials) ----------------
__global__ __launch_bounds__(BLOCK) void score_mesh(
    const int*   __restrict__ obj_id,
    const float* __restrict__ cam_K,
    const float* __restrict__ gt_R,
    const float* __restrict__ gt_t,
    const float* __restrict__ pr_R,
    const float* __restrict__ pr_t,
    const float* __restrict__ mesh,       // [NOBJ,M,3]
    float*       __restrict__ wsA)        // [N,MSPLIT,2] : ad, pj
{
    const int b   = blockIdx.x;
    const int n   = b >> 2;
    const int c   = b & (MSPLIT - 1);
    const int tid = threadIdx.x;

    const int obj = __builtin_amdgcn_readfirstlane(obj_id[n]);
    const float4* mp4 = (const float4*)(mesh + (size_t)obj * MPTS * 3);

    float4 MF[M_IT][3];
#pragma unroll
    for (int it = 0; it < M_IT; ++it) {
        const int k = c * (MPTS / MSPLIT / 4) + it * BLOCK + tid;
        MF[it][0] = mp4[k * 3 + 0];
        MF[it][1] = mp4[k * 3 + 1];
        MF[it][2] = mp4[k * 3 + 2];
    }

    float Ap[9], Ag[9], bp[3], bg[3];
    fuse_proj(cam_K, pr_R, pr_t, n, Ap, bp);
    fuse_proj(cam_K, gt_R, gt_t, n, Ag, bg);
    float dR[9], dt[3];
#pragma unroll
    for (int i = 0; i < 9; ++i) dR[i] = rfl(pr_R[n * 9 + i] - gt_R[n * 9 + i]);
#pragma unroll
    for (int i = 0; i < 3; ++i) dt[i] = rfl(pr_t[n * 3 + i] - gt_t[n * 3 + i]);

    float s_ad = 0.0f, s_pj = 0.0f;
#pragma unroll
    for (int it = 0; it < M_IT; ++it) {
        const float4 f0 = MF[it][0], f1 = MF[it][1], f2 = MF[it][2];
        const float px[4] = {f0.x, f0.w, f1.z, f2.y};
        const float py[4] = {f0.y, f1.x, f1.w, f2.z};
        const float pz[4] = {f0.z, f1.y, f2.x, f2.w};
#pragma unroll
        for (int j = 0; j < 4; ++j) {
            const float x = px[j], y = py[j], z = pz[j];
            const float dx = fmaf(dR[0], x, fmaf(dR[1], y, fmaf(dR[2], z, dt[0])));
            const float dy = fmaf(dR[3], x, fmaf(dR[4], y, fmaf(dR[5], z, dt[1])));
            const float dz = fmaf(dR[6], x, fmaf(dR[7], y, fmaf(dR[8], z, dt[2])));
            s_ad += fsqrt(fmaf(dx, dx, fmaf(dy, dy, dz * dz)));
            const float hpx = fmaf(Ap[0], x, fmaf(Ap[1], y, fmaf(Ap[2], z, bp[0])));
            const float hpy = fmaf(Ap[3], x, fmaf(Ap[4], y, fmaf(Ap[5], z, bp[1])));
            const float hpz = fmaf(Ap[6], x, fmaf(Ap[7], y, fmaf(Ap[8], z, bp[2])));
            const float hgx = fmaf(Ag[0], x, fmaf(Ag[1], y, fmaf(Ag[2], z, bg[0])));
            const float hgy = fmaf(Ag[3], x, fmaf(Ag[4], y, fmaf(Ag[5], z, bg[1])));
            const float hgz = fmaf(Ag[6], x, fmaf(Ag[7], y, fmaf(Ag[8], z, bg[2])));
            const float iwp = frcp(hpz), iwg = frcp(hgz);
            const float du = fmaf(hpx, iwp, -hgx * iwg);
            const float dv = fmaf(hpy, iwp, -hgy * iwg);
            s_pj += fsqrt(fmaf(du, du, dv * dv));
        }
    }

    float vals[2] = {s_ad, s_pj};
#pragma unroll
    for (int k = 0; k < 2; ++k)
#pragma unroll
        for (int off = 32; off > 0; off >>= 1)
            vals[k] += __shfl_down(vals[k], off, 64);

    __shared__ float red[2][NWAVE];
    const int wave = tid >> 6, lane = tid & 63;
    if (lane == 0) { red[0][wave] = vals[0]; red[1][wave] = vals[1]; }
    __syncthreads();
    if (tid == 0) {
        float ad = 0.0f, pj = 0.0f;
#pragma unroll
        for (int w = 0; w < NWAVE; ++w) { ad += red[0][w]; pj += red[1][w]; }
        wsA[(size_t)(n * MSPLIT + c) * 2 + 0] = ad;
        wsA[(size_t)(n * MSPLIT + c) * 2 + 1] = pj;
    }
}

// ---------------- kernel 3: final reduce + re/te ----------------
__global__ __launch_bounds__(256) void score_reduce(
    const float* __restrict__ wsA,       // [N,MSPLIT,2]
    const float* __restrict__ wsB,       // [N,PSPLIT,2]
    const int*   __restrict__ obj_id,
    const float* __restrict__ gt_R,
    const float* __restrict__ gt_t,
    const float* __restrict__ pr_R,
    const float* __restrict__ pr_t,
    const float* __restrict__ diam,
    float*       __restrict__ out)       // [5*N]
{
    const int n = blockIdx.x * blockDim.x + threadIdx.x;
    if (n >= NS) return;

    float ad = 0.0f, pj = 0.0f;
#pragma unroll
    for (int cb = 0; cb < MSPLIT; ++cb) {
        ad += wsA[(size_t)(n * MSPLIT + cb) * 2 + 0];
        pj += wsA[(size_t)(n * MSPLIT + cb) * 2 + 1];
    }
    float pv = 0.0f, m = 0.0f;
#pragma unroll
    for (int cb = 0; cb < PSPLIT; ++cb) {
        pv += wsB[(size_t)(n * PSPLIT + cb) * 2 + 0];
        m  += wsB[(size_t)(n * PSPLIT + cb) * 2 + 1];
    }

    float trace = 0.0f;
#pragma unroll
    for (int i = 0; i < 9; ++i) trace += pr_R[n * 9 + i] * gt_R[n * 9 + i];
    trace = fminf(fmaxf(trace, -1.0f), 3.0f);
    const float dx = pr_t[n * 3 + 0] - gt_t[n * 3 + 0];
    const float dy = pr_t[n * 3 + 1] - gt_t[n * 3 + 1];
    const float dz = pr_t[n * 3 + 2] - gt_t[n * 3 + 2];

    const float dia = diam[obj_id[n]];
    out[0 * NS + n] = acosf((trace - 1.0f) * 0.5f) * (180.0f / 3.14159265358979323846f);
    out[1 * NS + n] = sqrtf(dx * dx + dy * dy + dz * dz) * 100.0f;
    out[2 * NS + n] = ad * (1.0f / MPTS) / dia;
    out[3 * NS + n] = pj * (1.0f / MPTS);
    out[4 * NS + n] = pv / fmaxf(m, 1.0f);
}

extern "C" void kernel_launch(void* const* d_in, const int* in_sizes, int n_in,
                              void* d_out, int out_size, void* d_ws, size_t ws_size,
                              hipStream_t stream) {
    const int*   obj_id = (const int*)  d_in[0];
    const float* cam_K  = (const float*)d_in[1];
    const float* gt_R   = (const float*)d_in[2];
    const float* gt_t   = (const float*)d_in[3];
    const float* pr_R   = (const float*)d_in[4];
    const float* pr_t   = (const float*)d_in[5];
    const float* coord  = (const float*)d_in[6];
    const int*   mask   = (const int*)  d_in[7];
    const float* mesh   = (const float*)d_in[8];
    const float* diam   = (const float*)d_in[9];
    float* out = (float*)d_out;
    float* wsA = (float*)d_ws;                       // N*MSPLIT*2 floats
    float* wsB = wsA + (size_t)NS * MSPLIT * 2;      // N*PSPLIT*2 floats

    score_pixels<<<NS * PSPLIT, BLOCK, 0, stream>>>(cam_K, gt_R, gt_t, pr_R, pr_t,
                                                    coord, mask, wsB);
    score_mesh<<<NS * MSPLIT, BLOCK, 0, stream>>>(obj_id, cam_K, gt_R, gt_t, pr_R,
                                                  pr_t, mesh, wsA);
    score_reduce<<<(NS + 255) / 256, 256, 0, stream>>>(wsA, wsB, obj_id, gt_R, gt_t,
                                                       pr_R, pr_t, diam, out);
}

// Round 7
// 191.979 us; speedup vs baseline: 1.0342x; 1.0342x over previous
//
#include <hip/hip_runtime.h>
#include <math.h>

#define NS    512
#define NOBJ  16
#define MPTS  8192
#define HH    128
#define WW    128
#define HW    (HH * WW)
#define BLOCK 256
#define SPLIT 4                              // blocks per sample
#define NWAVE (BLOCK / 64)
#define P_IT  (HW / 4 / SPLIT / BLOCK)       // 4 pixel float4-groups per thread
#define M_IT  (MPTS / SPLIT / (BLOCK * 4))   // 2 mesh 4-point groups per thread

__device__ __forceinline__ float frcp(float x)  { return __builtin_amdgcn_rcpf(x); }
__device__ __forceinline__ float fsqrt(float x) { return __builtin_amdgcn_sqrtf(x); }
__device__ __forceinline__ float rfl(float x) {
    return __int_as_float(__builtin_amdgcn_readfirstlane(__float_as_int(x)));
}
__device__ __forceinline__ void sched_fence() {
#if __has_builtin(__builtin_amdgcn_sched_barrier)
    __builtin_amdgcn_sched_barrier(0);   // nothing crosses: loads stay hoisted
#endif
}

__device__ __forceinline__ void fuse_proj(const float* __restrict__ cam_K,
                                          const float* __restrict__ R,
                                          const float* __restrict__ t, int n,
                                          float A[9], float b[3]) {
    float K[9], Rr[9], tt[3];
#pragma unroll
    for (int i = 0; i < 9; ++i) { K[i] = cam_K[n * 9 + i]; Rr[i] = R[n * 9 + i]; }
#pragma unroll
    for (int i = 0; i < 3; ++i) tt[i] = t[n * 3 + i];
#pragma unroll
    for (int r = 0; r < 3; ++r) {
#pragma unroll
        for (int c = 0; c < 3; ++c)
            A[r * 3 + c] = rfl(K[r * 3 + 0] * Rr[0 * 3 + c]
                             + K[r * 3 + 1] * Rr[1 * 3 + c]
                             + K[r * 3 + 2] * Rr[2 * 3 + c]);
        b[r] = rfl(K[r * 3 + 0] * tt[0] + K[r * 3 + 1] * tt[1] + K[r * 3 + 2] * tt[2]);
    }
}

// waves_per_eu(3,4): scheduler pressure-target = 4 waves/EU (128 VGPR), hard
// floor 3 waves (170 VGPR) before spill. Stops the max-occupancy scheduler
// from sinking the batched loads back to their uses (R4: batch of 22 loads
// compiled to VGPR_Count=32 => zero MLP).
__global__ __attribute__((amdgpu_flat_work_group_size(BLOCK, BLOCK),
                          amdgpu_waves_per_eu(3, 4)))
void score_partial(
    const int*   __restrict__ obj_id,
    const float* __restrict__ cam_K,
    const float* __restrict__ gt_R,
    const float* __restrict__ gt_t,
    const float* __restrict__ pr_R,
    const float* __restrict__ pr_t,
    const float* __restrict__ coord,      // [N,3,H,W]
    const int*   __restrict__ mask,       // [N,1,H,W]
    const float* __restrict__ mesh,       // [NOBJ,M,3]
    float*       __restrict__ ws)         // [N,SPLIT,4] : ad, pj, pv, m
{
    const int b   = blockIdx.x;
    const int n   = b >> 2;
    const int c   = b & (SPLIT - 1);
    const int tid = threadIdx.x;

    // ---- scalar constants first (s_load/lgkm path, tiny) ----
    float Ap[9], Ag[9], bp[3], bg[3], dR[9], dt[3];
    fuse_proj(cam_K, pr_R, pr_t, n, Ap, bp);
    fuse_proj(cam_K, gt_R, gt_t, n, Ag, bg);
#pragma unroll
    for (int i = 0; i < 9; ++i) dR[i] = rfl(pr_R[n * 9 + i] - gt_R[n * 9 + i]);
#pragma unroll
    for (int i = 0; i < 3; ++i) dt[i] = rfl(pr_t[n * 3 + i] - gt_t[n * 3 + i]);
    const int obj = __builtin_amdgcn_readfirstlane(obj_id[n]);

    // ---- issue ALL 22 loads, consumption order == issue order ----
    const float* cx = coord + (size_t)n * 3 * HW;
    const float4* cx4 = (const float4*)cx;
    const float4* cy4 = (const float4*)(cx + HW);
    const float4* cz4 = (const float4*)(cx + 2 * HW);
    const int4*   mk4 = (const int4*)(mask + (size_t)n * HW);
    const float4* mp4 = (const float4*)(mesh + (size_t)obj * MPTS * 3);

    float4 AX[P_IT], AY[P_IT], AZ[P_IT];
    int4   AM[P_IT];
#pragma unroll
    for (int it = 0; it < P_IT; ++it) {
        const int p = c * (HW / 4 / SPLIT) + it * BLOCK + tid;
        AX[it] = cx4[p];
        AY[it] = cy4[p];
        AZ[it] = cz4[p];
        AM[it] = mk4[p];
    }
    float4 MF[M_IT][3];
#pragma unroll
    for (int it = 0; it < M_IT; ++it) {
        const int k = c * (MPTS / SPLIT / 4) + it * BLOCK + tid;
        MF[it][0] = mp4[k * 3 + 0];
        MF[it][1] = mp4[k * 3 + 1];
        MF[it][2] = mp4[k * 3 + 2];
    }

    sched_fence();   // pin: all loads issued before any consuming compute

    // ---- phase 2 compute (pixel loads, issued first, consumed first) ----
    float s_pv = 0.0f, s_m = 0.0f;
#pragma unroll
    for (int it = 0; it < P_IT; ++it) {
        const float xs[4] = {AX[it].x, AX[it].y, AX[it].z, AX[it].w};
        const float ys[4] = {AY[it].x, AY[it].y, AY[it].z, AY[it].w};
        const float zs[4] = {AZ[it].x, AZ[it].y, AZ[it].z, AZ[it].w};
        const int   ms[4] = {AM[it].x, AM[it].y, AM[it].z, AM[it].w};
#pragma unroll
        for (int j = 0; j < 4; ++j) {
            const float x = xs[j], y = ys[j], z = zs[j];
            const float hpx = fmaf(Ap[0], x, fmaf(Ap[1], y, fmaf(Ap[2], z, bp[0])));
            const float hpy = fmaf(Ap[3], x, fmaf(Ap[4], y, fmaf(Ap[5], z, bp[1])));
            const float hpz = fmaf(Ap[6], x, fmaf(Ap[7], y, fmaf(Ap[8], z, bp[2])));
            const float hgx = fmaf(Ag[0], x, fmaf(Ag[1], y, fmaf(Ag[2], z, bg[0])));
            const float hgy = fmaf(Ag[3], x, fmaf(Ag[4], y, fmaf(Ag[5], z, bg[1])));
            const float hgz = fmaf(Ag[6], x, fmaf(Ag[7], y, fmaf(Ag[8], z, bg[2])));
            const float iwp = frcp(hpz), iwg = frcp(hgz);
            const float du = fmaf(hpx, iwp, -hgx * iwg);
            const float dv = fmaf(hpy, iwp, -hgy * iwg);
            const float d  = fsqrt(fmaf(du, du, dv * dv));
            const float fm = (ms[j] != 0) ? 1.0f : 0.0f;
            s_pv += d * fm;
            s_m  += fm;
        }
    }

    // ---- phase 1 compute (mesh loads, issued last, consumed last) ----
    float s_ad = 0.0f, s_pj = 0.0f;
#pragma unroll
    for (int it = 0; it < M_IT; ++it) {
        const float4 f0 = MF[it][0], f1 = MF[it][1], f2 = MF[it][2];
        const float px[4] = {f0.x, f0.w, f1.z, f2.y};
        const float py[4] = {f0.y, f1.x, f1.w, f2.z};
        const float pz[4] = {f0.z, f1.y, f2.x, f2.w};
#pragma unroll
        for (int j = 0; j < 4; ++j) {
            const float x = px[j], y = py[j], z = pz[j];
            const float dx = fmaf(dR[0], x, fmaf(dR[1], y, fmaf(dR[2], z, dt[0])));
            const float dy = fmaf(dR[3], x, fmaf(dR[4], y, fmaf(dR[5], z, dt[1])));
            const float dz = fmaf(dR[6], x, fmaf(dR[7], y, fmaf(dR[8], z, dt[2])));
            s_ad += fsqrt(fmaf(dx, dx, fmaf(dy, dy, dz * dz)));
            const float hpx = fmaf(Ap[0], x, fmaf(Ap[1], y, fmaf(Ap[2], z, bp[0])));
            const float hpy = fmaf(Ap[3], x, fmaf(Ap[4], y, fmaf(Ap[5], z, bp[1])));
            const float hpz = fmaf(Ap[6], x, fmaf(Ap[7], y, fmaf(Ap[8], z, bp[2])));
            const float hgx = fmaf(Ag[0], x, fmaf(Ag[1], y, fmaf(Ag[2], z, bg[0])));
            const float hgy = fmaf(Ag[3], x, fmaf(Ag[4], y, fmaf(Ag[5], z, bg[1])));
            const float hgz = fmaf(Ag[6], x, fmaf(Ag[7], y, fmaf(Ag[8], z, bg[2])));
            const float iwp = frcp(hpz), iwg = frcp(hgz);
            const float du = fmaf(hpx, iwp, -hgx * iwg);
            const float dv = fmaf(hpy, iwp, -hgy * iwg);
            s_pj += fsqrt(fmaf(du, du, dv * dv));
        }
    }

    // ---- block reduction of 4 sums ----
    float vals[4] = {s_ad, s_pj, s_pv, s_m};
#pragma unroll
    for (int k = 0; k < 4; ++k)
#pragma unroll
        for (int off = 32; off > 0; off >>= 1)
            vals[k] += __shfl_down(vals[k], off, 64);

    __shared__ float red[4][NWAVE];
    const int wave = tid >> 6, lane = tid & 63;
    if (lane == 0) {
#pragma unroll
        for (int k = 0; k < 4; ++k) red[k][wave] = vals[k];
    }
    __syncthreads();
    if (tid == 0) {
#pragma unroll
        for (int k = 0; k < 4; ++k) {
            float s = 0.0f;
#pragma unroll
            for (int w = 0; w < NWAVE; ++w) s += red[k][w];
            ws[(size_t)(n * SPLIT + c) * 4 + k] = s;
        }
    }
}

// ---------------- final reduce + re/te ----------------
__global__ __launch_bounds__(256) void score_reduce(
    const float* __restrict__ ws,        // [N,SPLIT,4]
    const int*   __restrict__ obj_id,
    const float* __restrict__ gt_R,
    const float* __restrict__ gt_t,
    const float* __restrict__ pr_R,
    const float* __restrict__ pr_t,
    const float* __restrict__ diam,
    float*       __restrict__ out)       // [5*N]
{
    const int n = blockIdx.x * blockDim.x + threadIdx.x;
    if (n >= NS) return;

    float ad = 0.0f, pj = 0.0f, pv = 0.0f, m = 0.0f;
#pragma unroll
    for (int cb = 0; cb < SPLIT; ++cb) {
        const float* p = ws + (size_t)(n * SPLIT + cb) * 4;
        ad += p[0]; pj += p[1]; pv += p[2]; m += p[3];
    }

    float trace = 0.0f;
#pragma unroll
    for (int i = 0; i < 9; ++i) trace += pr_R[n * 9 + i] * gt_R[n * 9 + i];
    trace = fminf(fmaxf(trace, -1.0f), 3.0f);
    const float dx = pr_t[n * 3 + 0] - gt_t[n * 3 + 0];
    const float dy = pr_t[n * 3 + 1] - gt_t[n * 3 + 1];
    const float dz = pr_t[n * 3 + 2] - gt_t[n * 3 + 2];

    const float dia = diam[obj_id[n]];
    out[0 * NS + n] = acosf((trace - 1.0f) * 0.5f) * (180.0f / 3.14159265358979323846f);
    out[1 * NS + n] = sqrtf(dx * dx + dy * dy + dz * dz) * 100.0f;
    out[2 * NS + n] = ad * (1.0f / MPTS) / dia;
    out[3 * NS + n] = pj * (1.0f / MPTS);
    out[4 * NS + n] = pv / fmaxf(m, 1.0f);
}

extern "C" void kernel_launch(void* const* d_in, const int* in_sizes, int n_in,
                              void* d_out, int out_size, void* d_ws, size_t ws_size,
                              hipStream_t stream) {
    const int*   obj_id = (const int*)  d_in[0];
    const float* cam_K  = (const float*)d_in[1];
    const float* gt_R   = (const float*)d_in[2];
    const float* gt_t   = (const float*)d_in[3];
    const float* pr_R   = (const float*)d_in[4];
    const float* pr_t   = (const float*)d_in[5];
    const float* coord  = (const float*)d_in[6];
    const int*   mask   = (const int*)  d_in[7];
    const float* mesh   = (const float*)d_in[8];
    const float* diam   = (const float*)d_in[9];
    float* out = (float*)d_out;
    float* ws  = (float*)d_ws;   // N*SPLIT*4 floats = 32 KB

    score_partial<<<NS * SPLIT, BLOCK, 0, stream>>>(obj_id, cam_K, gt_R, gt_t, pr_R,
                                                    pr_t, coord, mask, mesh, ws);
    score_reduce<<<(NS + 255) / 256, 256, 0, stream>>>(ws, obj_id, gt_R, gt_t,
                                                       pr_R, pr_t, diam, out);
}

// Round 8
// 184.351 us; speedup vs baseline: 1.0770x; 1.0414x over previous
//
#include <hip/hip_runtime.h>
#include <math.h>

#define NS    512
#define NOBJ  16
#define MPTS  8192
#define HH    128
#define WW    128
#define HW    (HH * WW)
#define BLOCK 512
#define NWAVE (BLOCK / 64)
#define P_IT  (HW / 4 / BLOCK)        // 8 pixel float4-tiles per thread
#define M_IT  (MPTS / 4 / BLOCK)      // 4 mesh 4-point groups per thread

typedef float f4 __attribute__((ext_vector_type(4)));
typedef int   i4 __attribute__((ext_vector_type(4)));

__device__ __forceinline__ float frcp(float x)  { return __builtin_amdgcn_rcpf(x); }
__device__ __forceinline__ float fsqrt(float x) { return __builtin_amdgcn_sqrtf(x); }
__device__ __forceinline__ float rfl(float x) {
    return __int_as_float(__builtin_amdgcn_readfirstlane(__float_as_int(x)));
}
__device__ __forceinline__ void sched_fence() {
#if __has_builtin(__builtin_amdgcn_sched_barrier)
    __builtin_amdgcn_sched_barrier(0);
#endif
}
__device__ __forceinline__ f4 ntl_f4(const f4* p) {
#if __has_builtin(__builtin_nontemporal_load)
    return __builtin_nontemporal_load(p);
#else
    return *p;
#endif
}
__device__ __forceinline__ i4 ntl_i4(const i4* p) {
#if __has_builtin(__builtin_nontemporal_load)
    return __builtin_nontemporal_load(p);
#else
    return *p;
#endif
}

__device__ __forceinline__ void fuse_proj(const float* __restrict__ cam_K,
                                          const float* __restrict__ R,
                                          const float* __restrict__ t, int n,
                                          float A[9], float b[3]) {
    float K[9], Rr[9], tt[3];
#pragma unroll
    for (int i = 0; i < 9; ++i) { K[i] = cam_K[n * 9 + i]; Rr[i] = R[n * 9 + i]; }
#pragma unroll
    for (int i = 0; i < 3; ++i) tt[i] = t[n * 3 + i];
#pragma unroll
    for (int r = 0; r < 3; ++r) {
#pragma unroll
        for (int c = 0; c < 3; ++c)
            A[r * 3 + c] = rfl(K[r * 3 + 0] * Rr[0 * 3 + c]
                             + K[r * 3 + 1] * Rr[1 * 3 + c]
                             + K[r * 3 + 2] * Rr[2 * 3 + c]);
        b[r] = rfl(K[r * 3 + 0] * tt[0] + K[r * 3 + 1] * tt[1] + K[r * 3 + 2] * tt[2]);
    }
}

// One block per sample (512 blocks x 512 threads = 2 blocks/CU, all co-resident).
// Pixel phase: depth-3 rolling prefetch (steady 12 loads/wave in flight).
__global__ __attribute__((amdgpu_flat_work_group_size(BLOCK, BLOCK),
                          amdgpu_waves_per_eu(4, 4)))
void score_kernel(
    const int*   __restrict__ obj_id,
    const float* __restrict__ cam_K,
    const float* __restrict__ gt_R,
    const float* __restrict__ gt_t,
    const float* __restrict__ pr_R,
    const float* __restrict__ pr_t,
    const float* __restrict__ coord,      // [N,3,H,W]
    const int*   __restrict__ mask,       // [N,1,H,W]
    const float* __restrict__ mesh,       // [NOBJ,M,3]
    const float* __restrict__ diam,
    float*       __restrict__ out)        // [5*N]
{
    const int n   = blockIdx.x;
    const int tid = threadIdx.x;

    // ---- constants (scalar path) ----
    float Ap[9], Ag[9], bp[3], bg[3], dR[9], dt[3];
    fuse_proj(cam_K, pr_R, pr_t, n, Ap, bp);
    fuse_proj(cam_K, gt_R, gt_t, n, Ag, bg);
#pragma unroll
    for (int i = 0; i < 9; ++i) dR[i] = rfl(pr_R[n * 9 + i] - gt_R[n * 9 + i]);
#pragma unroll
    for (int i = 0; i < 3; ++i) dt[i] = rfl(pr_t[n * 3 + i] - gt_t[n * 3 + i]);
    const int obj = __builtin_amdgcn_readfirstlane(obj_id[n]);

    const float* cx = coord + (size_t)n * 3 * HW;
    const f4* cx4 = (const f4*)cx;
    const f4* cy4 = (const f4*)(cx + HW);
    const f4* cz4 = (const f4*)(cx + 2 * HW);
    const i4* mk4 = (const i4*)(mask + (size_t)n * HW);

    // ---- pixel phase: 8 tiles, rolling pipeline depth 3 (4-slot rotation) ----
    f4 AX[4], AY[4], AZ[4];
    i4 AM[4];
#pragma unroll
    for (int t = 0; t < 3; ++t) {       // prologue: tiles 0,1,2 in flight
        const int p = t * BLOCK + tid;
        AX[t] = ntl_f4(cx4 + p);
        AY[t] = ntl_f4(cy4 + p);
        AZ[t] = ntl_f4(cz4 + p);
        AM[t] = ntl_i4(mk4 + p);
    }

    float s_pv = 0.0f, s_m = 0.0f;
#pragma unroll
    for (int it = 0; it < P_IT; ++it) {
        if (it + 3 < P_IT) {            // issue tile it+3 into freed slot
            const int t = it + 3;
            const int s = t & 3;
            const int p = t * BLOCK + tid;
            AX[s] = ntl_f4(cx4 + p);
            AY[s] = ntl_f4(cy4 + p);
            AZ[s] = ntl_f4(cz4 + p);
            AM[s] = ntl_i4(mk4 + p);
        }
        sched_fence();                  // keep prefetch above the compute
        const int s = it & 3;
        const float xs[4] = {AX[s].x, AX[s].y, AX[s].z, AX[s].w};
        const float ys[4] = {AY[s].x, AY[s].y, AY[s].z, AY[s].w};
        const float zs[4] = {AZ[s].x, AZ[s].y, AZ[s].z, AZ[s].w};
        const int   ms[4] = {AM[s].x, AM[s].y, AM[s].z, AM[s].w};
#pragma unroll
        for (int j = 0; j < 4; ++j) {
            const float x = xs[j], y = ys[j], z = zs[j];
            const float hpx = fmaf(Ap[0], x, fmaf(Ap[1], y, fmaf(Ap[2], z, bp[0])));
            const float hpy = fmaf(Ap[3], x, fmaf(Ap[4], y, fmaf(Ap[5], z, bp[1])));
            const float hpz = fmaf(Ap[6], x, fmaf(Ap[7], y, fmaf(Ap[8], z, bp[2])));
            const float hgx = fmaf(Ag[0], x, fmaf(Ag[1], y, fmaf(Ag[2], z, bg[0])));
            const float hgy = fmaf(Ag[3], x, fmaf(Ag[4], y, fmaf(Ag[5], z, bg[1])));
            const float hgz = fmaf(Ag[6], x, fmaf(Ag[7], y, fmaf(Ag[8], z, bg[2])));
            const float iwp = frcp(hpz), iwg = frcp(hgz);
            const float du = fmaf(hpx, iwp, -hgx * iwg);
            const float dv = fmaf(hpy, iwp, -hgy * iwg);
            const float d  = fsqrt(fmaf(du, du, dv * dv));
            const float fm = (ms[j] != 0) ? 1.0f : 0.0f;
            s_pv += d * fm;
            s_m  += fm;
        }
    }

    // ---- mesh phase: issue all 12 loads, consume in order ----
    const f4* mp4 = (const f4*)(mesh + (size_t)obj * MPTS * 3);
    f4 MF[M_IT][3];
#pragma unroll
    for (int it = 0; it < M_IT; ++it) {
        const int k = it * BLOCK + tid;
        MF[it][0] = mp4[k * 3 + 0];
        MF[it][1] = mp4[k * 3 + 1];
        MF[it][2] = mp4[k * 3 + 2];
    }
    sched_fence();

    float s_ad = 0.0f, s_pj = 0.0f;
#pragma unroll
    for (int it = 0; it < M_IT; ++it) {
        const f4 f0 = MF[it][0], f1 = MF[it][1], f2 = MF[it][2];
        const float px[4] = {f0.x, f0.w, f1.z, f2.y};
        const float py[4] = {f0.y, f1.x, f1.w, f2.z};
        const float pz[4] = {f0.z, f1.y, f2.x, f2.w};
#pragma unroll
        for (int j = 0; j < 4; ++j) {
            const float x = px[j], y = py[j], z = pz[j];
            const float dx = fmaf(dR[0], x, fmaf(dR[1], y, fmaf(dR[2], z, dt[0])));
            const float dy = fmaf(dR[3], x, fmaf(dR[4], y, fmaf(dR[5], z, dt[1])));
            const float dz = fmaf(dR[6], x, fmaf(dR[7], y, fmaf(dR[8], z, dt[2])));
            s_ad += fsqrt(fmaf(dx, dx, fmaf(dy, dy, dz * dz)));
            const float hpx = fmaf(Ap[0], x, fmaf(Ap[1], y, fmaf(Ap[2], z, bp[0])));
            const float hpy = fmaf(Ap[3], x, fmaf(Ap[4], y, fmaf(Ap[5], z, bp[1])));
            const float hpz = fmaf(Ap[6], x, fmaf(Ap[7], y, fmaf(Ap[8], z, bp[2])));
            const float hgx = fmaf(Ag[0], x, fmaf(Ag[1], y, fmaf(Ag[2], z, bg[0])));
            const float hgy = fmaf(Ag[3], x, fmaf(Ag[4], y, fmaf(Ag[5], z, bg[1])));
            const float hgz = fmaf(Ag[6], x, fmaf(Ag[7], y, fmaf(Ag[8], z, bg[2])));
            const float iwp = frcp(hpz), iwg = frcp(hgz);
            const float du = fmaf(hpx, iwp, -hgx * iwg);
            const float dv = fmaf(hpy, iwp, -hgy * iwg);
            s_pj += fsqrt(fmaf(du, du, dv * dv));
        }
    }

    // ---- block reduction ----
    float vals[4] = {s_ad, s_pj, s_pv, s_m};
#pragma unroll
    for (int k = 0; k < 4; ++k)
#pragma unroll
        for (int off = 32; off > 0; off >>= 1)
            vals[k] += __shfl_down(vals[k], off, 64);

    __shared__ float red[4][NWAVE];
    const int wave = tid >> 6, lane = tid & 63;
    if (lane == 0) {
#pragma unroll
        for (int k = 0; k < 4; ++k) red[k][wave] = vals[k];
    }
    __syncthreads();

    if (tid == 0) {
        float tot[4];
#pragma unroll
        for (int k = 0; k < 4; ++k) {
            float s = 0.0f;
#pragma unroll
            for (int w = 0; w < NWAVE; ++w) s += red[k][w];
            tot[k] = s;
        }
        float Rg9[9], Rp9[9];
#pragma unroll
        for (int i = 0; i < 9; ++i) { Rg9[i] = gt_R[n * 9 + i]; Rp9[i] = pr_R[n * 9 + i]; }
        float trace = 0.0f;
#pragma unroll
        for (int i = 0; i < 9; ++i) trace += Rp9[i] * Rg9[i];
        trace = fminf(fmaxf(trace, -1.0f), 3.0f);
        const float te = sqrtf(dt[0] * dt[0] + dt[1] * dt[1] + dt[2] * dt[2]) * 100.0f;

        out[0 * NS + n] = acosf((trace - 1.0f) * 0.5f) * (180.0f / 3.14159265358979323846f);
        out[1 * NS + n] = te;
        out[2 * NS + n] = tot[0] * (1.0f / MPTS) / diam[obj];
        out[3 * NS + n] = tot[1] * (1.0f / MPTS);
        out[4 * NS + n] = tot[2] / fmaxf(tot[3], 1.0f);
    }
}

extern "C" void kernel_launch(void* const* d_in, const int* in_sizes, int n_in,
                              void* d_out, int out_size, void* d_ws, size_t ws_size,
                              hipStream_t stream) {
    const int*   obj_id = (const int*)  d_in[0];
    const float* cam_K  = (const float*)d_in[1];
    const float* gt_R   = (const float*)d_in[2];
    const float* gt_t   = (const float*)d_in[3];
    const float* pr_R   = (const float*)d_in[4];
    const float* pr_t   = (const float*)d_in[5];
    const float* coord  = (const float*)d_in[6];
    const int*   mask   = (const int*)  d_in[7];
    const float* mesh   = (const float*)d_in[8];
    const float* diam   = (const float*)d_in[9];
    float* out = (float*)d_out;

    score_kernel<<<NS, BLOCK, 0, stream>>>(obj_id, cam_K, gt_R, gt_t, pr_R, pr_t,
                                           coord, mask, mesh, diam, out);
}